// Round 6
// baseline (350.811 us; speedup 1.0000x reference)
//
#include <hip/hip_runtime.h>
#include <hip/hip_bf16.h>
#include <math.h>

#define NEG_SLOPE 0.2f

__device__ __forceinline__ float lrelu(float x){ return x > 0.f ? x : NEG_SLOPE * x; }
__device__ __forceinline__ unsigned short f2bf(float f){
  __hip_bfloat16 h = __float2bfloat16(f);
  return __builtin_bit_cast(unsigned short, h);
}
__device__ __forceinline__ float b2f(unsigned short u){
  return __builtin_bit_cast(float, (unsigned)u << 16);
}

typedef short bf16x8 __attribute__((ext_vector_type(8)));
typedef float f32x4 __attribute__((ext_vector_type(4)));

// ---------------- CSR build ----------------
__global__ void k_count(const int* __restrict__ dst, int* __restrict__ deg, int E){
  int e = blockIdx.x*256 + threadIdx.x;
  if (e < E) atomicAdd(&deg[dst[e]], 1);
}

__global__ __launch_bounds__(256) void k_scan1(const int* __restrict__ deg, int* __restrict__ bsum, int n){
  int tid = threadIdx.x;
  int base = blockIdx.x*1024 + tid*4;
  int s = 0;
  #pragma unroll
  for (int j=0;j<4;j++){ int idx = base+j; if (idx < n) s += deg[idx]; }
  #pragma unroll
  for (int off=32; off; off>>=1) s += __shfl_xor(s, off);
  __shared__ int ws[4];
  if ((tid&63)==0) ws[tid>>6] = s;
  __syncthreads();
  if (tid==0) bsum[blockIdx.x] = ws[0]+ws[1]+ws[2]+ws[3];
}

__global__ void k_scan2(const int* __restrict__ bsum, int* __restrict__ boff,
                        int* __restrict__ rowptr, int nb, int n){
  int lane = threadIdx.x;
  int v = (lane < nb) ? bsum[lane] : 0;
  int inc = v;
  #pragma unroll
  for (int off=1; off<64; off<<=1){ int t = __shfl_up(inc, off); if (lane >= off) inc += t; }
  if (lane < nb) boff[lane] = inc - v;
  if (lane == 63) rowptr[n] = inc;
}

__global__ __launch_bounds__(256) void k_scan3(const int* __restrict__ deg, const int* __restrict__ boff,
    int* __restrict__ rowptr, int* __restrict__ nxt, int n){
  int tid = threadIdx.x; int lane = tid & 63, w = tid >> 6;
  int base = blockIdx.x*1024 + tid*4;
  int v[4]; int s = 0;
  #pragma unroll
  for (int j=0;j<4;j++){ int idx = base+j; v[j] = (idx < n) ? deg[idx] : 0; s += v[j]; }
  int inc = s;
  #pragma unroll
  for (int off=1; off<64; off<<=1){ int t = __shfl_up(inc, off); if (lane >= off) inc += t; }
  __shared__ int ws[4];
  if (lane == 63) ws[w] = inc;
  __syncthreads();
  int run = boff[blockIdx.x];
  for (int ww=0; ww<w; ww++) run += ws[ww];
  run += inc - s;
  #pragma unroll
  for (int j=0;j<4;j++){ int idx = base+j; if (idx < n){ rowptr[idx] = run; nxt[idx] = run; run += v[j]; } }
}

__global__ void k_scatter(const int* __restrict__ src, const int* __restrict__ dst,
                          int* __restrict__ nxt, int* __restrict__ srcs, int E){
  int e = blockIdx.x*256 + threadIdx.x;
  if (e < E){
    int pos = atomicAdd(&nxt[dst[e]], 1);
    srcs[pos] = src[e];
  }
}

// ---------------- weight transpose fp32 -> bf16 ----------------
__global__ void k_wt(const float* __restrict__ W, unsigned short* __restrict__ Wt, int NCreal){
  int c = blockIdx.x, k = threadIdx.x, K = blockDim.x;
  float v = (c < NCreal) ? W[(size_t)k*NCreal + c] : 0.f;
  Wt[(size_t)c*K + k] = f2bf(v);
}

// ---------------- layer-1 GEMM (fp32 A staged->bf16) + fused attention dots ------
// tile 64 rows x 256 cols (full width), K=128. 4 waves, wave w owns cols w*64..+63
// (= heads 2w, 2w+1). Epilogue: h1b bf16 write + asrc/adst via 16-lane shfl reduce.
__global__ __launch_bounds__(256) void gemm1_att(
    const float* __restrict__ x, const unsigned short* __restrict__ Bt,
    unsigned short* __restrict__ C, const float* __restrict__ att_s,
    const float* __restrict__ att_d, float* __restrict__ asrc,
    float* __restrict__ adst, int M){
  __shared__ unsigned short sA[64][40];
  __shared__ unsigned short sB[256][40];
  const int tid = threadIdx.x;
  const int wid = tid >> 6, lane = tid & 63;
  const int r0 = blockIdx.x * 64;
  const int fr = lane & 15, fk = (lane >> 4) * 8;
  f32x4 acc[4][4] = {};

  for (int k0 = 0; k0 < 128; k0 += 32){
    // stage A: 64 rows x 32 k, from fp32, convert to bf16. 512 float4 loads.
    #pragma unroll
    for (int t=0; t<2; t++){
      int id = tid + t*256;          // 0..511
      int r = id >> 3, q = id & 7;   // row, k-quad
      float4 v = make_float4(0.f,0.f,0.f,0.f);
      int row = r0 + r;
      if (row < M) v = ((const float4*)(x + (size_t)row*128))[(k0>>2) + q];
      ushort4 o; o.x=f2bf(v.x); o.y=f2bf(v.y); o.z=f2bf(v.z); o.w=f2bf(v.w);
      *(ushort4*)&sA[r][q*4] = o;
    }
    // stage B: 256 rows x 32 k (bf16) = 1024 uint4 loads -> 4 per thread.
    #pragma unroll
    for (int t=0; t<4; t++){
      int id = tid + t*256;          // 0..1023
      int r = id >> 2, lk = (id & 3) * 8;
      uint4 vb = *(const uint4*)(Bt + (size_t)r*128 + k0 + lk);
      *(uint4*)&sB[r][lk] = vb;
    }
    __syncthreads();
    bf16x8 a[4], b[4];
    #pragma unroll
    for (int mi=0; mi<4; mi++) a[mi] = *(const bf16x8*)&sA[mi*16 + fr][fk];
    #pragma unroll
    for (int ni=0; ni<4; ni++) b[ni] = *(const bf16x8*)&sB[wid*64 + ni*16 + fr][fk];
    #pragma unroll
    for (int mi=0; mi<4; mi++)
      #pragma unroll
      for (int ni=0; ni<4; ni++)
        acc[mi][ni] = __builtin_amdgcn_mfma_f32_16x16x32_bf16(a[mi], b[ni], acc[mi][ni], 0,0,0);
    __syncthreads();
  }

  // preload att values for this wave's cols: col = wid*64 + ni*16 + fr
  // head = 2*wid + (ni>>1); idx-in-head = (ni&1)*16 + fr
  float avs[4], avd[4];
  #pragma unroll
  for (int ni=0; ni<4; ni++){
    int idx = (2*wid + (ni>>1))*32 + (ni&1)*16 + fr;
    avs[ni] = att_s[idx];
    avd[ni] = att_d[idx];
  }

  #pragma unroll
  for (int mi=0; mi<4; mi++){
    #pragma unroll
    for (int j=0; j<4; j++){
      int row = r0 + mi*16 + (lane>>4)*4 + j;
      // C write (4 cols per (mi,j) across ni)
      #pragma unroll
      for (int ni=0; ni<4; ni++){
        int col = wid*64 + ni*16 + fr;
        if (row < M) C[(size_t)row*256 + col] = f2bf(acc[mi][ni][j]);
      }
      // attention partial dots, reduce over fr (16 lanes, xor<16 stays in group)
      float s0 = acc[mi][0][j]*avs[0] + acc[mi][1][j]*avs[1];
      float s1 = acc[mi][2][j]*avs[2] + acc[mi][3][j]*avs[3];
      float d0 = acc[mi][0][j]*avd[0] + acc[mi][1][j]*avd[1];
      float d1 = acc[mi][2][j]*avd[2] + acc[mi][3][j]*avd[3];
      #pragma unroll
      for (int mk=1; mk<16; mk<<=1){
        s0 += __shfl_xor(s0, mk); s1 += __shfl_xor(s1, mk);
        d0 += __shfl_xor(d0, mk); d1 += __shfl_xor(d1, mk);
      }
      if ((lane & 15) == 0 && row < M){
        asrc[(size_t)row*8 + 2*wid    ] = s0;
        asrc[(size_t)row*8 + 2*wid + 1] = s1;
        adst[(size_t)row*8 + 2*wid    ] = d0;
        adst[(size_t)row*8 + 2*wid + 1] = d1;
      }
    }
  }
}

// ---------------- generic bf16 MFMA GEMM (layer 2): C bf16 = A @ Bt^T ----------------
__global__ __launch_bounds__(256) void gemm_mfma(
    const unsigned short* __restrict__ A, const unsigned short* __restrict__ Bt,
    unsigned short* __restrict__ C, int M, int K, int ldc){
  __shared__ unsigned short sA[64][40];
  __shared__ unsigned short sB[64][40];
  const int tid = threadIdx.x;
  const int wid = tid >> 6, lane = tid & 63;
  const int r0 = blockIdx.x * 64, c0 = blockIdx.y * 64;
  const int wr = wid >> 1, wc = wid & 1;
  const int lr = tid >> 2;
  const int lk = (tid & 3) * 8;
  const int fr = lane & 15, fk = (lane >> 4) * 8;
  f32x4 acc[2][2] = {};

  for (int k0 = 0; k0 < K; k0 += 32){
    uint4 va = make_uint4(0,0,0,0);
    int row = r0 + lr;
    if (row < M) va = *(const uint4*)(A + (size_t)row*K + k0 + lk);
    *(uint4*)&sA[lr][lk] = va;
    uint4 vb = *(const uint4*)(Bt + (size_t)(c0 + lr)*K + k0 + lk);
    *(uint4*)&sB[lr][lk] = vb;
    __syncthreads();
    bf16x8 a0 = *(const bf16x8*)&sA[wr*32 + fr][fk];
    bf16x8 a1 = *(const bf16x8*)&sA[wr*32 + 16 + fr][fk];
    bf16x8 b0 = *(const bf16x8*)&sB[wc*32 + fr][fk];
    bf16x8 b1 = *(const bf16x8*)&sB[wc*32 + 16 + fr][fk];
    acc[0][0] = __builtin_amdgcn_mfma_f32_16x16x32_bf16(a0, b0, acc[0][0], 0,0,0);
    acc[0][1] = __builtin_amdgcn_mfma_f32_16x16x32_bf16(a0, b1, acc[0][1], 0,0,0);
    acc[1][0] = __builtin_amdgcn_mfma_f32_16x16x32_bf16(a1, b0, acc[1][0], 0,0,0);
    acc[1][1] = __builtin_amdgcn_mfma_f32_16x16x32_bf16(a1, b1, acc[1][1], 0,0,0);
    __syncthreads();
  }
  #pragma unroll
  for (int mi=0; mi<2; mi++){
    int rowb = r0 + wr*32 + mi*16 + (lane>>4)*4;
    #pragma unroll
    for (int ni=0; ni<2; ni++){
      int col = c0 + wc*32 + ni*16 + fr;
      #pragma unroll
      for (int j=0;j<4;j++){
        int row = rowb + j;
        if (row < M) C[(size_t)row*ldc + col] = f2bf(acc[mi][ni][j]);
      }
    }
  }
}

// ---------------- attention dots for layer 2 (h2 bf16, 64 cols incl zero pad) -----
__global__ void k_att2(const unsigned short* __restrict__ h, const float* __restrict__ att_s,
    const float* __restrict__ att_d, float* __restrict__ asrc, float* __restrict__ adst, int n){
  int id = blockIdx.x*256 + threadIdx.x;   // id = node
  if (id >= n) return;
  const unsigned short* hv = h + (size_t)id*64;
  float s = 0.f, d = 0.f;
  #pragma unroll
  for (int q=0; q<5; q++){
    ushort4 u0 = ((const ushort4*)hv)[q*2];
    ushort4 u1 = ((const ushort4*)hv)[q*2+1];
    float v0=b2f(u0.x), v1=b2f(u0.y), v2=b2f(u0.z), v3=b2f(u0.w);
    float v4=b2f(u1.x), v5=b2f(u1.y), v6=b2f(u1.z), v7=b2f(u1.w);
    float4 a0 = ((const float4*)att_s)[q*2], a1 = ((const float4*)att_s)[q*2+1];
    float4 d0 = ((const float4*)att_d)[q*2], d1 = ((const float4*)att_d)[q*2+1];
    s += v0*a0.x + v1*a0.y + v2*a0.z + v3*a0.w + v4*a1.x + v5*a1.y + v6*a1.z + v7*a1.w;
    d += v0*d0.x + v1*d0.y + v2*d0.z + v3*d0.w + v4*d1.x + v5*d1.y + v6*d1.z + v7*d1.w;
  }
  asrc[id] = s; adst[id] = d;
}

// ---------------- layer-1 aggregation: 2 waves/node (channel halves), online softmax
__global__ __launch_bounds__(256) void k_agg1(
    const unsigned short* __restrict__ h1, const float* __restrict__ asrc,
    const float* __restrict__ adst, const int* __restrict__ rowptr,
    const int* __restrict__ srcs, const float* __restrict__ bias,
    unsigned short* __restrict__ zb, int n){
  int gw = (blockIdx.x*256 + threadIdx.x) >> 6;
  int lane = threadIdx.x & 63;
  int i = gw >> 1, half = gw & 1;
  if (i >= n) return;
  int hd = half*4 + (lane >> 4);          // head for this lane's 2 channels
  float adsti = adst[(size_t)i*8 + hd];
  float m = lrelu(asrc[(size_t)i*8 + hd] + adsti);   // self logit; p_self = 1
  float ssum = 1.f;
  unsigned hv = ((const unsigned*)(h1 + (size_t)i*256))[half*64 + lane];
  float accx = b2f((unsigned short)(hv & 0xffff));
  float accy = b2f((unsigned short)(hv >> 16));
  int e0 = rowptr[i], e1 = rowptr[i+1];
  int e = e0;
  for (; e + 8 <= e1; e += 8){
    int sx[8]; unsigned vv[8]; float ll[8];
    #pragma unroll
    for (int j=0;j<8;j++) sx[j] = srcs[e+j];
    #pragma unroll
    for (int j=0;j<8;j++) vv[j] = ((const unsigned*)(h1 + (size_t)sx[j]*256))[half*64 + lane];
    #pragma unroll
    for (int j=0;j<8;j++) ll[j] = lrelu(asrc[(size_t)sx[j]*8 + hd] + adsti);
    float gm = ll[0];
    #pragma unroll
    for (int j=1;j<8;j++) gm = fmaxf(gm, ll[j]);
    float mn = fmaxf(m, gm);
    float r = __expf(m - mn); m = mn;
    ssum *= r; accx *= r; accy *= r;
    #pragma unroll
    for (int j=0;j<8;j++){
      float p = __expf(ll[j] - m);
      ssum += p;
      accx += p * b2f((unsigned short)(vv[j] & 0xffff));
      accy += p * b2f((unsigned short)(vv[j] >> 16));
    }
  }
  for (; e < e1; ++e){
    int s = srcs[e];
    unsigned v = ((const unsigned*)(h1 + (size_t)s*256))[half*64 + lane];
    float l = lrelu(asrc[(size_t)s*8 + hd] + adsti);
    float mn = fmaxf(m, l);
    float r = __expf(m - mn);
    float p = __expf(l - mn); m = mn;
    ssum = ssum*r + p;
    accx = accx*r + p * b2f((unsigned short)(v & 0xffff));
    accy = accy*r + p * b2f((unsigned short)(v >> 16));
  }
  float inv = 1.f / ssum;
  float2 b = ((const float2*)bias)[half*64 + lane];
  unsigned ob = (unsigned)f2bf(fmaxf(fmaf(accx, inv, b.x), 0.f))
              | ((unsigned)f2bf(fmaxf(fmaf(accy, inv, b.y), 0.f)) << 16);
  ((unsigned*)(zb + (size_t)i*256))[half*64 + lane] = ob;
}

// ---------------- layer-2 aggregation + log_softmax (bf16 gathers) ----------------
__global__ __launch_bounds__(256) void k_agg2(
    const unsigned short* __restrict__ h2, const float* __restrict__ asrc,
    const float* __restrict__ adst, const int* __restrict__ rowptr,
    const int* __restrict__ srcs, const float* __restrict__ bias,
    float* __restrict__ out, int n){
  int wid = (blockIdx.x*256 + threadIdx.x) >> 6;
  int lane = threadIdx.x & 63;
  if (wid >= n) return;
  int i = wid;
  bool act = lane < 40;
  float adsti = adst[i];
  float m = lrelu(asrc[i] + adsti);
  float ssum = 1.f;
  float acc = b2f(h2[(size_t)i*64 + lane]);   // cols 40..63 are zeros
  int e0 = rowptr[i], e1 = rowptr[i+1];
  int e = e0;
  for (; e + 8 <= e1; e += 8){
    int sx[8]; float vv[8], ll[8];
    #pragma unroll
    for (int j=0;j<8;j++) sx[j] = srcs[e+j];
    #pragma unroll
    for (int j=0;j<8;j++) vv[j] = b2f(h2[(size_t)sx[j]*64 + lane]);
    #pragma unroll
    for (int j=0;j<8;j++) ll[j] = lrelu(asrc[sx[j]] + adsti);
    float gm = ll[0];
    #pragma unroll
    for (int j=1;j<8;j++) gm = fmaxf(gm, ll[j]);
    float mn = fmaxf(m, gm);
    float r = __expf(m - mn); m = mn;
    ssum *= r; acc *= r;
    #pragma unroll
    for (int j=0;j<8;j++){
      float p = __expf(ll[j] - m);
      ssum += p;
      acc += p * vv[j];
    }
  }
  for (; e < e1; ++e){
    int s = srcs[e];
    float v = b2f(h2[(size_t)s*64 + lane]);
    float l = lrelu(asrc[s] + adsti);
    float mn = fmaxf(m, l);
    float r = __expf(m - mn);
    float p = __expf(l - mn); m = mn;
    ssum = ssum*r + p;
    acc  = acc*r + p*v;
  }
  float val = act ? (acc/ssum + bias[lane]) : -INFINITY;
  float mx = val;
  #pragma unroll
  for (int off=32; off; off>>=1) mx = fmaxf(mx, __shfl_xor(mx, off));
  float ex = act ? __expf(val - mx) : 0.f;
  float se = ex;
  #pragma unroll
  for (int off=32; off; off>>=1) se += __shfl_xor(se, off);
  if (act) out[(size_t)i*40 + lane] = val - mx - __logf(se);
}

extern "C" void kernel_launch(void* const* d_in, const int* in_sizes, int n_in,
                              void* d_out, int out_size, void* d_ws, size_t ws_size,
                              hipStream_t stream){
  const float* x   = (const float*)d_in[0];
  const int*   ei  = (const int*)d_in[1];
  const float* W1  = (const float*)d_in[2];
  const float* as1 = (const float*)d_in[3];
  const float* ad1 = (const float*)d_in[4];
  const float* b1  = (const float*)d_in[5];
  const float* W2  = (const float*)d_in[6];
  const float* as2 = (const float*)d_in[7];
  const float* ad2 = (const float*)d_in[8];
  const float* b2  = (const float*)d_in[9];
  float* out = (float*)d_out;

  const int N = in_sizes[0] / 128;
  const int E = in_sizes[1] / 2;
  const int* srcI = ei;
  const int* dstI = ei + E;

  char* ws = (char*)d_ws;
  size_t off = 0;
  auto alloc = [&](size_t bytes){ void* p = ws + off; off += (bytes + 255) & ~(size_t)255; return p; };
  unsigned short* h1b = (unsigned short*)alloc((size_t)N*256*2);
  unsigned short* zb  = (unsigned short*)alloc((size_t)N*256*2);
  unsigned short* h2b = (unsigned short*)alloc((size_t)N*64*2);
  unsigned short* W1t = (unsigned short*)alloc((size_t)256*128*2);
  unsigned short* W2t = (unsigned short*)alloc((size_t)64*256*2);
  float* asrc1 = (float*)alloc((size_t)N*8*4);
  float* adst1 = (float*)alloc((size_t)N*8*4);
  float* asrc2 = (float*)alloc((size_t)N*4);
  float* adst2 = (float*)alloc((size_t)N*4);
  int* deg     = (int*)alloc((size_t)N*4);
  int* rowptr  = (int*)alloc((size_t)(N+1)*4);
  int* nxt     = (int*)alloc((size_t)N*4);
  int* srcs    = (int*)alloc((size_t)E*4);
  int* bsum    = (int*)alloc(256*4);
  int* boff    = (int*)alloc(256*4);
  (void)ws_size; (void)n_in; (void)out_size;

  const int nb = (N + 1023)/1024;
  hipMemsetAsync(deg, 0, (size_t)N*4, stream);
  int eb = (E + 255)/256;
  k_count <<<eb, 256, 0, stream>>>(dstI, deg, E);
  k_scan1 <<<nb, 256, 0, stream>>>(deg, bsum, N);
  k_scan2 <<<1, 64, 0, stream>>>(bsum, boff, rowptr, nb, N);
  k_scan3 <<<nb, 256, 0, stream>>>(deg, boff, rowptr, nxt, N);
  k_scatter<<<eb, 256, 0, stream>>>(srcI, dstI, nxt, srcs, E);

  // weight transposes
  k_wt <<<256, 128, 0, stream>>>(W1, W1t, 256);
  k_wt <<<64, 256, 0, stream>>>(W2, W2t, 40);

  // layer 1: fused GEMM + attention dots
  gemm1_att<<<(N + 63)/64, 256, 0, stream>>>(x, W1t, h1b, as1, ad1, asrc1, adst1, N);
  k_agg1<<<(2*N + 3)/4, 256, 0, stream>>>(h1b, asrc1, adst1, rowptr, srcs, b1, zb, N);

  // layer 2
  dim3 g2((N + 63)/64, 1);
  gemm_mfma<<<g2, 256, 0, stream>>>(zb, W2t, h2b, N, 256, 64);
  k_att2<<<(N + 255)/256, 256, 0, stream>>>(h2b, as2, ad2, asrc2, adst2, N);
  k_agg2<<<(N + 3)/4, 256, 0, stream>>>(h2b, asrc2, adst2, rowptr, srcs, b2, out, N);
}

// Round 7
// 324.710 us; speedup vs baseline: 1.0804x; 1.0804x over previous
//
#include <hip/hip_runtime.h>
#include <hip/hip_bf16.h>
#include <math.h>

#define NEG_SLOPE 0.2f

__device__ __forceinline__ float lrelu(float x){ return x > 0.f ? x : NEG_SLOPE * x; }
__device__ __forceinline__ unsigned short f2bf(float f){
  __hip_bfloat16 h = __float2bfloat16(f);
  return __builtin_bit_cast(unsigned short, h);
}
__device__ __forceinline__ float b2f(unsigned short u){
  return __builtin_bit_cast(float, (unsigned)u << 16);
}

typedef short bf16x8 __attribute__((ext_vector_type(8)));
typedef float f32x4 __attribute__((ext_vector_type(4)));

// ---------------- CSR build ----------------
__global__ void k_count(const int* __restrict__ dst, int* __restrict__ deg, int E){
  int e = blockIdx.x*256 + threadIdx.x;
  if (e < E) atomicAdd(&deg[dst[e]], 1);
}

__global__ __launch_bounds__(256) void k_scan1(const int* __restrict__ deg, int* __restrict__ bsum, int n){
  int tid = threadIdx.x;
  int base = blockIdx.x*1024 + tid*4;
  int s = 0;
  #pragma unroll
  for (int j=0;j<4;j++){ int idx = base+j; if (idx < n) s += deg[idx]; }
  #pragma unroll
  for (int off=32; off; off>>=1) s += __shfl_xor(s, off);
  __shared__ int ws[4];
  if ((tid&63)==0) ws[tid>>6] = s;
  __syncthreads();
  if (tid==0) bsum[blockIdx.x] = ws[0]+ws[1]+ws[2]+ws[3];
}

__global__ void k_scan2(const int* __restrict__ bsum, int* __restrict__ boff,
                        int* __restrict__ rowptr, int nb, int n){
  int lane = threadIdx.x;
  int v = (lane < nb) ? bsum[lane] : 0;
  int inc = v;
  #pragma unroll
  for (int off=1; off<64; off<<=1){ int t = __shfl_up(inc, off); if (lane >= off) inc += t; }
  if (lane < nb) boff[lane] = inc - v;
  if (lane == 63) rowptr[n] = inc;
}

__global__ __launch_bounds__(256) void k_scan3(const int* __restrict__ deg, const int* __restrict__ boff,
    int* __restrict__ rowptr, int* __restrict__ nxt, int n){
  int tid = threadIdx.x; int lane = tid & 63, w = tid >> 6;
  int base = blockIdx.x*1024 + tid*4;
  int v[4]; int s = 0;
  #pragma unroll
  for (int j=0;j<4;j++){ int idx = base+j; v[j] = (idx < n) ? deg[idx] : 0; s += v[j]; }
  int inc = s;
  #pragma unroll
  for (int off=1; off<64; off<<=1){ int t = __shfl_up(inc, off); if (lane >= off) inc += t; }
  __shared__ int ws[4];
  if (lane == 63) ws[w] = inc;
  __syncthreads();
  int run = boff[blockIdx.x];
  for (int ww=0; ww<w; ww++) run += ws[ww];
  run += inc - s;
  #pragma unroll
  for (int j=0;j<4;j++){ int idx = base+j; if (idx < n){ rowptr[idx] = run; nxt[idx] = run; run += v[j]; } }
}

__global__ void k_scatter(const int* __restrict__ src, const int* __restrict__ dst,
                          int* __restrict__ nxt, int* __restrict__ srcs, int E){
  int e = blockIdx.x*256 + threadIdx.x;
  if (e < E){
    int pos = atomicAdd(&nxt[dst[e]], 1);
    srcs[pos] = src[e];
  }
}

// ---------------- weight transpose fp32 -> bf16 ----------------
__global__ void k_wt(const float* __restrict__ W, unsigned short* __restrict__ Wt, int NCreal){
  int c = blockIdx.x, k = threadIdx.x, K = blockDim.x;
  float v = (c < NCreal) ? W[(size_t)k*NCreal + c] : 0.f;
  Wt[(size_t)c*K + k] = f2bf(v);
}

// ---------------- layer-1 GEMM (fp32 A staged->bf16) + fused attention dots ------
__global__ __launch_bounds__(256) void gemm1_att(
    const float* __restrict__ x, const unsigned short* __restrict__ Bt,
    unsigned short* __restrict__ C, const float* __restrict__ att_s,
    const float* __restrict__ att_d, float* __restrict__ asrc,
    float* __restrict__ adst, int M){
  __shared__ unsigned short sA[64][40];
  __shared__ unsigned short sB[256][40];
  const int tid = threadIdx.x;
  const int wid = tid >> 6, lane = tid & 63;
  const int r0 = blockIdx.x * 64;
  const int fr = lane & 15, fk = (lane >> 4) * 8;
  f32x4 acc[4][4] = {};

  for (int k0 = 0; k0 < 128; k0 += 32){
    #pragma unroll
    for (int t=0; t<2; t++){
      int id = tid + t*256;          // 0..511
      int r = id >> 3, q = id & 7;   // row, k-quad
      float4 v = make_float4(0.f,0.f,0.f,0.f);
      int row = r0 + r;
      if (row < M) v = ((const float4*)(x + (size_t)row*128))[(k0>>2) + q];
      ushort4 o; o.x=f2bf(v.x); o.y=f2bf(v.y); o.z=f2bf(v.z); o.w=f2bf(v.w);
      *(ushort4*)&sA[r][q*4] = o;
    }
    #pragma unroll
    for (int t=0; t<4; t++){
      int id = tid + t*256;          // 0..1023
      int r = id >> 2, lk = (id & 3) * 8;
      uint4 vb = *(const uint4*)(Bt + (size_t)r*128 + k0 + lk);
      *(uint4*)&sB[r][lk] = vb;
    }
    __syncthreads();
    bf16x8 a[4], b[4];
    #pragma unroll
    for (int mi=0; mi<4; mi++) a[mi] = *(const bf16x8*)&sA[mi*16 + fr][fk];
    #pragma unroll
    for (int ni=0; ni<4; ni++) b[ni] = *(const bf16x8*)&sB[wid*64 + ni*16 + fr][fk];
    #pragma unroll
    for (int mi=0; mi<4; mi++)
      #pragma unroll
      for (int ni=0; ni<4; ni++)
        acc[mi][ni] = __builtin_amdgcn_mfma_f32_16x16x32_bf16(a[mi], b[ni], acc[mi][ni], 0,0,0);
    __syncthreads();
  }

  float avs[4], avd[4];
  #pragma unroll
  for (int ni=0; ni<4; ni++){
    int idx = (2*wid + (ni>>1))*32 + (ni&1)*16 + fr;
    avs[ni] = att_s[idx];
    avd[ni] = att_d[idx];
  }

  #pragma unroll
  for (int mi=0; mi<4; mi++){
    #pragma unroll
    for (int j=0; j<4; j++){
      int row = r0 + mi*16 + (lane>>4)*4 + j;
      #pragma unroll
      for (int ni=0; ni<4; ni++){
        int col = wid*64 + ni*16 + fr;
        if (row < M) C[(size_t)row*256 + col] = f2bf(acc[mi][ni][j]);
      }
      float s0 = acc[mi][0][j]*avs[0] + acc[mi][1][j]*avs[1];
      float s1 = acc[mi][2][j]*avs[2] + acc[mi][3][j]*avs[3];
      float d0 = acc[mi][0][j]*avd[0] + acc[mi][1][j]*avd[1];
      float d1 = acc[mi][2][j]*avd[2] + acc[mi][3][j]*avd[3];
      #pragma unroll
      for (int mk=1; mk<16; mk<<=1){
        s0 += __shfl_xor(s0, mk); s1 += __shfl_xor(s1, mk);
        d0 += __shfl_xor(d0, mk); d1 += __shfl_xor(d1, mk);
      }
      if ((lane & 15) == 0 && row < M){
        asrc[(size_t)row*8 + 2*wid    ] = s0;
        asrc[(size_t)row*8 + 2*wid + 1] = s1;
        adst[(size_t)row*8 + 2*wid    ] = d0;
        adst[(size_t)row*8 + 2*wid + 1] = d1;
      }
    }
  }
}

// ---------------- generic bf16 MFMA GEMM (layer 2): C bf16 = A @ Bt^T ----------------
__global__ __launch_bounds__(256) void gemm_mfma(
    const unsigned short* __restrict__ A, const unsigned short* __restrict__ Bt,
    unsigned short* __restrict__ C, int M, int K, int ldc){
  __shared__ unsigned short sA[64][40];
  __shared__ unsigned short sB[64][40];
  const int tid = threadIdx.x;
  const int wid = tid >> 6, lane = tid & 63;
  const int r0 = blockIdx.x * 64, c0 = blockIdx.y * 64;
  const int wr = wid >> 1, wc = wid & 1;
  const int lr = tid >> 2;
  const int lk = (tid & 3) * 8;
  const int fr = lane & 15, fk = (lane >> 4) * 8;
  f32x4 acc[2][2] = {};

  for (int k0 = 0; k0 < K; k0 += 32){
    uint4 va = make_uint4(0,0,0,0);
    int row = r0 + lr;
    if (row < M) va = *(const uint4*)(A + (size_t)row*K + k0 + lk);
    *(uint4*)&sA[lr][lk] = va;
    uint4 vb = *(const uint4*)(Bt + (size_t)(c0 + lr)*K + k0 + lk);
    *(uint4*)&sB[lr][lk] = vb;
    __syncthreads();
    bf16x8 a0 = *(const bf16x8*)&sA[wr*32 + fr][fk];
    bf16x8 a1 = *(const bf16x8*)&sA[wr*32 + 16 + fr][fk];
    bf16x8 b0 = *(const bf16x8*)&sB[wc*32 + fr][fk];
    bf16x8 b1 = *(const bf16x8*)&sB[wc*32 + 16 + fr][fk];
    acc[0][0] = __builtin_amdgcn_mfma_f32_16x16x32_bf16(a0, b0, acc[0][0], 0,0,0);
    acc[0][1] = __builtin_amdgcn_mfma_f32_16x16x32_bf16(a0, b1, acc[0][1], 0,0,0);
    acc[1][0] = __builtin_amdgcn_mfma_f32_16x16x32_bf16(a1, b0, acc[1][0], 0,0,0);
    acc[1][1] = __builtin_amdgcn_mfma_f32_16x16x32_bf16(a1, b1, acc[1][1], 0,0,0);
    __syncthreads();
  }
  #pragma unroll
  for (int mi=0; mi<2; mi++){
    int rowb = r0 + wr*32 + mi*16 + (lane>>4)*4;
    #pragma unroll
    for (int ni=0; ni<2; ni++){
      int col = c0 + wc*32 + ni*16 + fr;
      #pragma unroll
      for (int j=0;j<4;j++){
        int row = rowb + j;
        if (row < M) C[(size_t)row*ldc + col] = f2bf(acc[mi][ni][j]);
      }
    }
  }
}

// ---------------- attention dots for layer 2 (h2 bf16, 64 cols incl zero pad) -----
__global__ void k_att2(const unsigned short* __restrict__ h, const float* __restrict__ att_s,
    const float* __restrict__ att_d, float* __restrict__ asrc, float* __restrict__ adst, int n){
  int id = blockIdx.x*256 + threadIdx.x;   // id = node
  if (id >= n) return;
  const unsigned short* hv = h + (size_t)id*64;
  float s = 0.f, d = 0.f;
  #pragma unroll
  for (int q=0; q<5; q++){
    ushort4 u0 = ((const ushort4*)hv)[q*2];
    ushort4 u1 = ((const ushort4*)hv)[q*2+1];
    float v0=b2f(u0.x), v1=b2f(u0.y), v2=b2f(u0.z), v3=b2f(u0.w);
    float v4=b2f(u1.x), v5=b2f(u1.y), v6=b2f(u1.z), v7=b2f(u1.w);
    float4 a0 = ((const float4*)att_s)[q*2], a1 = ((const float4*)att_s)[q*2+1];
    float4 d0 = ((const float4*)att_d)[q*2], d1 = ((const float4*)att_d)[q*2+1];
    s += v0*a0.x + v1*a0.y + v2*a0.z + v3*a0.w + v4*a1.x + v5*a1.y + v6*a1.z + v7*a1.w;
    d += v0*d0.x + v1*d0.y + v2*d0.z + v3*d0.w + v4*d1.x + v5*d1.y + v6*d1.z + v7*d1.w;
  }
  asrc[id] = s; adst[id] = d;
}

// ---------------- layer-1 aggregation: wave/node, NO-MAX softmax (exp direct) ------
__global__ __launch_bounds__(256) void k_agg1(
    const unsigned short* __restrict__ h1, const float* __restrict__ asrc,
    const float* __restrict__ adst, const int* __restrict__ rowptr,
    const int* __restrict__ srcs, const float* __restrict__ bias,
    unsigned short* __restrict__ zb, int n){
  int i = (blockIdx.x*256 + threadIdx.x) >> 6;
  int lane = threadIdx.x & 63;
  if (i >= n) return;
  int hd = lane >> 3;                 // channels lane*4..+3 are all in head lane/8
  float adsti = adst[(size_t)i*8 + hd];
  float pself = __expf(lrelu(asrc[(size_t)i*8 + hd] + adsti));
  float ssum = pself;
  uint2 hs = ((const uint2*)(h1 + (size_t)i*256))[lane];
  float4 acc;
  acc.x = pself * b2f((unsigned short)(hs.x & 0xffff));
  acc.y = pself * b2f((unsigned short)(hs.x >> 16));
  acc.z = pself * b2f((unsigned short)(hs.y & 0xffff));
  acc.w = pself * b2f((unsigned short)(hs.y >> 16));
  int e0 = rowptr[i], e1 = rowptr[i+1];
  int e = e0;
  for (; e + 8 <= e1; e += 8){
    int sx[8]; uint2 vv[8]; float pp[8];
    #pragma unroll
    for (int j=0;j<8;j++) sx[j] = srcs[e+j];
    #pragma unroll
    for (int j=0;j<8;j++) vv[j] = ((const uint2*)(h1 + (size_t)sx[j]*256))[lane];
    #pragma unroll
    for (int j=0;j<8;j++) pp[j] = __expf(lrelu(asrc[(size_t)sx[j]*8 + hd] + adsti));
    #pragma unroll
    for (int j=0;j<8;j++){
      float p = pp[j];
      ssum += p;
      acc.x += p * b2f((unsigned short)(vv[j].x & 0xffff));
      acc.y += p * b2f((unsigned short)(vv[j].x >> 16));
      acc.z += p * b2f((unsigned short)(vv[j].y & 0xffff));
      acc.w += p * b2f((unsigned short)(vv[j].y >> 16));
    }
  }
  for (; e < e1; ++e){
    int s = srcs[e];
    uint2 v = ((const uint2*)(h1 + (size_t)s*256))[lane];
    float p = __expf(lrelu(asrc[(size_t)s*8 + hd] + adsti));
    ssum += p;
    acc.x += p * b2f((unsigned short)(v.x & 0xffff));
    acc.y += p * b2f((unsigned short)(v.x >> 16));
    acc.z += p * b2f((unsigned short)(v.y & 0xffff));
    acc.w += p * b2f((unsigned short)(v.y >> 16));
  }
  float inv = 1.f / ssum;
  float4 b = ((const float4*)bias)[lane];
  ushort4 ob;
  ob.x = f2bf(fmaxf(fmaf(acc.x, inv, b.x), 0.f));
  ob.y = f2bf(fmaxf(fmaf(acc.y, inv, b.y), 0.f));
  ob.z = f2bf(fmaxf(fmaf(acc.z, inv, b.z), 0.f));
  ob.w = f2bf(fmaxf(fmaf(acc.w, inv, b.w), 0.f));
  ((ushort4*)(zb + (size_t)i*256))[lane] = ob;
}

// ---------------- layer-2 aggregation + log_softmax, NO-MAX softmax ----------------
__global__ __launch_bounds__(256) void k_agg2(
    const unsigned short* __restrict__ h2, const float* __restrict__ asrc,
    const float* __restrict__ adst, const int* __restrict__ rowptr,
    const int* __restrict__ srcs, const float* __restrict__ bias,
    float* __restrict__ out, int n){
  int wid = (blockIdx.x*256 + threadIdx.x) >> 6;
  int lane = threadIdx.x & 63;
  if (wid >= n) return;
  int i = wid;
  bool act = lane < 40;
  float adsti = adst[i];
  float pself = __expf(lrelu(asrc[i] + adsti));
  float ssum = pself;
  float acc = pself * b2f(h2[(size_t)i*64 + lane]);   // cols 40..63 are zeros
  int e0 = rowptr[i], e1 = rowptr[i+1];
  int e = e0;
  for (; e + 8 <= e1; e += 8){
    int sx[8]; float vv[8], pp[8];
    #pragma unroll
    for (int j=0;j<8;j++) sx[j] = srcs[e+j];
    #pragma unroll
    for (int j=0;j<8;j++) vv[j] = b2f(h2[(size_t)sx[j]*64 + lane]);
    #pragma unroll
    for (int j=0;j<8;j++) pp[j] = __expf(lrelu(asrc[sx[j]] + adsti));
    #pragma unroll
    for (int j=0;j<8;j++){
      ssum += pp[j];
      acc += pp[j] * vv[j];
    }
  }
  for (; e < e1; ++e){
    int s = srcs[e];
    float v = b2f(h2[(size_t)s*64 + lane]);
    float p = __expf(lrelu(asrc[s] + adsti));
    ssum += p;
    acc += p * v;
  }
  float val = act ? (acc/ssum + bias[lane]) : -INFINITY;
  float mx = val;
  #pragma unroll
  for (int off=32; off; off>>=1) mx = fmaxf(mx, __shfl_xor(mx, off));
  float ex = act ? __expf(val - mx) : 0.f;
  float se = ex;
  #pragma unroll
  for (int off=32; off; off>>=1) se += __shfl_xor(se, off);
  if (act) out[(size_t)i*40 + lane] = val - mx - __logf(se);
}

extern "C" void kernel_launch(void* const* d_in, const int* in_sizes, int n_in,
                              void* d_out, int out_size, void* d_ws, size_t ws_size,
                              hipStream_t stream){
  const float* x   = (const float*)d_in[0];
  const int*   ei  = (const int*)d_in[1];
  const float* W1  = (const float*)d_in[2];
  const float* as1 = (const float*)d_in[3];
  const float* ad1 = (const float*)d_in[4];
  const float* b1  = (const float*)d_in[5];
  const float* W2  = (const float*)d_in[6];
  const float* as2 = (const float*)d_in[7];
  const float* ad2 = (const float*)d_in[8];
  const float* b2  = (const float*)d_in[9];
  float* out = (float*)d_out;

  const int N = in_sizes[0] / 128;
  const int E = in_sizes[1] / 2;
  const int* srcI = ei;
  const int* dstI = ei + E;

  char* ws = (char*)d_ws;
  size_t off = 0;
  auto alloc = [&](size_t bytes){ void* p = ws + off; off += (bytes + 255) & ~(size_t)255; return p; };
  unsigned short* h1b = (unsigned short*)alloc((size_t)N*256*2);
  unsigned short* zb  = (unsigned short*)alloc((size_t)N*256*2);
  unsigned short* h2b = (unsigned short*)alloc((size_t)N*64*2);
  unsigned short* W1t = (unsigned short*)alloc((size_t)256*128*2);
  unsigned short* W2t = (unsigned short*)alloc((size_t)64*256*2);
  float* asrc1 = (float*)alloc((size_t)N*8*4);
  float* adst1 = (float*)alloc((size_t)N*8*4);
  float* asrc2 = (float*)alloc((size_t)N*4);
  float* adst2 = (float*)alloc((size_t)N*4);
  int* deg     = (int*)alloc((size_t)N*4);
  int* rowptr  = (int*)alloc((size_t)(N+1)*4);
  int* nxt     = (int*)alloc((size_t)N*4);
  int* srcs    = (int*)alloc((size_t)E*4);
  int* bsum    = (int*)alloc(256*4);
  int* boff    = (int*)alloc(256*4);
  (void)ws_size; (void)n_in; (void)out_size;

  const int nb = (N + 1023)/1024;
  hipMemsetAsync(deg, 0, (size_t)N*4, stream);
  int eb = (E + 255)/256;
  k_count <<<eb, 256, 0, stream>>>(dstI, deg, E);
  k_scan1 <<<nb, 256, 0, stream>>>(deg, bsum, N);
  k_scan2 <<<1, 64, 0, stream>>>(bsum, boff, rowptr, nb, N);
  k_scan3 <<<nb, 256, 0, stream>>>(deg, boff, rowptr, nxt, N);
  k_scatter<<<eb, 256, 0, stream>>>(srcI, dstI, nxt, srcs, E);

  // weight transposes
  k_wt <<<256, 128, 0, stream>>>(W1, W1t, 256);
  k_wt <<<64, 256, 0, stream>>>(W2, W2t, 40);

  // layer 1: fused GEMM + attention dots
  gemm1_att<<<(N + 63)/64, 256, 0, stream>>>(x, W1t, h1b, as1, ad1, asrc1, adst1, N);
  k_agg1<<<(N + 3)/4, 256, 0, stream>>>(h1b, asrc1, adst1, rowptr, srcs, b1, zb, N);

  // layer 2
  dim3 g2((N + 63)/64, 1);
  gemm_mfma<<<g2, 256, 0, stream>>>(zb, W2t, h2b, N, 256, 64);
  k_att2<<<(N + 255)/256, 256, 0, stream>>>(h2b, as2, ad2, asrc2, adst2, N);
  k_agg2<<<(N + 3)/4, 256, 0, stream>>>(h2b, asrc2, adst2, rowptr, srcs, b2, out, N);
}